// Round 20
// baseline (787.670 us; speedup 1.0000x reference)
//
#include <hip/hip_runtime.h>
#include <hip/hip_fp16.h>

#define D 128
#define E_PER 500000
#define TOT_ROWS 669000
#define CH 4096
#define NR64 64
#define SLABSZ ((size_t)223000 * 256)

typedef _Float16 f16;
typedef _Float16 f16x8 __attribute__((ext_vector_type(8)));
typedef _Float16 f16x4 __attribute__((ext_vector_type(4)));
typedef _Float16 f16x2 __attribute__((ext_vector_type(2)));
typedef float f32x4 __attribute__((ext_vector_type(4)));

// Per-edge-type row-segment bases in the concatenated CSR arrays (k = s*3 + t).
__device__ const int d_SEGB[9] = {0, 200000, 203000, 223000, 423000, 426000,
                                  446000, 646000, 649000};
__device__ const int d_XB[3] = {0, 200000, 203000};
__device__ const int d_NC[3] = {200000, 3000, 20000};
// gemm tile ranges per t (64-row tiles): t0 3125, t1 47, t2 313
__device__ const int d_T64LO[3] = {0, 3125, 3172};
__device__ const int d_T64HI[3] = {3125, 3172, 3485};
// aggregate block offsets per k: t0/t2 = 16 rows/block (group-per-row);
// t1 = 1 row/block (16 edge slots)
__device__ const int d_AOFF[10] = {0, 12500, 15500, 16750, 29250, 32250,
                                   33500, 46000, 49000, 50250};

// XOR swizzle for the A tile in LDS (row stride 256B f16).
__device__ __forceinline__ unsigned a_swz(int row, int byteoff) {
    return (unsigned)(row * 256 + byteoff) ^ (unsigned)((row & 7) << 4);
}

// map global gemm tile (64-row) -> (t, local tile)
__device__ __forceinline__ void tile_map64(int g, int& t, int& tl) {
    if (g < 3125)      { t = 0; tl = g; }
    else if (g < 3172) { t = 1; tl = g - 3125; }
    else               { t = 2; tl = g - 3172; }
}

// ---------------------------------------------------------------- precast W^T
__global__ void precast(const float* __restrict__ W1,
                        const float* __restrict__ W2,
                        f16* __restrict__ Wth) {
    int i = blockIdx.x * 256 + threadIdx.x;
    if (i >= 2 * 3 * 128 * 128) return;
    int layer = i / 49152;
    int rem = i - layer * 49152;
    int s = rem / 16384;
    int r2 = rem & 16383;
    int kk = r2 >> 7;
    int c  = r2 & 127;
    const float* W = layer ? W2 : W1;
    Wth[(((size_t)layer * 3 + s) * 128 + c) * 128 + kk] = (f16)W[((size_t)s * 128 + kk) * 128 + c];
}

// ==================== CSR pass 1: bucket histogram + FUSED x->f16 cast
__global__ __launch_bounds__(256) void bucket_count(const int* __restrict__ ei,
                                                    int* __restrict__ bcnt,
                                                    const float* __restrict__ x0,
                                                    const float* __restrict__ x1,
                                                    const float* __restrict__ x2,
                                                    f16* __restrict__ y) {
    __shared__ int hist[256];
    int k = blockIdx.y, tid = threadIdx.x;
    const int* dstp = ei + (size_t)k * 2 * E_PER + E_PER;
    unsigned Nt = (unsigned)d_NC[k % 3];
    int base = blockIdx.x * CH;
    int hi = min(base + CH, E_PER);
    hist[tid] = 0;
    __syncthreads();
    for (int i = base + tid; i < hi; i += 256) {
        unsigned b = ((unsigned)dstp[i] << 8) / Nt;
        atomicAdd(&hist[b], 1);
    }
    __syncthreads();
    if (hist[tid]) atomicAdd(&bcnt[k * 256 + tid], hist[tid]);

    // ---- fused cast: grid-stride over all 223000*16 f16x8 slots
    const int nb = gridDim.x * gridDim.y;                 // 1107
    const int bid = blockIdx.y * gridDim.x + blockIdx.x;
    const int total = 223000 * 16;
    for (int i = bid * 256 + tid; i < total; i += nb * 256) {
        int row = i >> 4, c8 = i & 15;
        const float* src;
        if (row < 200000)      src = x0 + (size_t)row * D;
        else if (row < 203000) src = x1 + (size_t)(row - 200000) * D;
        else                   src = x2 + (size_t)(row - 203000) * D;
        f32x4 v0 = ((const f32x4*)src)[c8 * 2];
        f32x4 v1 = ((const f32x4*)src)[c8 * 2 + 1];
        f16x8 h;
        #pragma unroll
        for (int j = 0; j < 4; ++j) { h[j] = (f16)v0[j]; h[4 + j] = (f16)v1[j]; }
        ((f16x8*)(y + (size_t)row * D))[c8] = h;
    }
}

__global__ void bucket_scan(const int* __restrict__ bcnt,
                            int* __restrict__ bbase, int* __restrict__ bcursor) {
    __shared__ int sb[256];
    int t = threadIdx.x;
    int loc[9];
    int s = 0;
    #pragma unroll
    for (int j = 0; j < 9; ++j) { loc[j] = bcnt[t * 9 + j]; s += loc[j]; }
    sb[t] = s; __syncthreads();
    int v = s;
    for (int off = 1; off < 256; off <<= 1) {
        int u = (t >= off) ? sb[t - off] : 0;
        __syncthreads();
        sb[t] += u;
        __syncthreads();
    }
    int pre = sb[t] - v;
    #pragma unroll
    for (int j = 0; j < 9; ++j) {
        bbase[t * 9 + j] = pre;
        bcursor[t * 9 + j] = pre;
        pre += loc[j];
    }
    if (t == 255) bbase[2304] = pre;
}

__global__ __launch_bounds__(256) void bin_scatter(const int* __restrict__ ei,
                                                   int* __restrict__ bcursor,
                                                   int2* __restrict__ binned) {
    __shared__ int hist[256], gb[256], cur[256];
    int k = blockIdx.y, tid = threadIdx.x;
    const int* srcp = ei + (size_t)k * 2 * E_PER;
    const int* dstp = srcp + E_PER;
    unsigned Nt = (unsigned)d_NC[k % 3];
    int base = blockIdx.x * CH;
    int hi = min(base + CH, E_PER);
    hist[tid] = 0;
    __syncthreads();
    for (int i = base + tid; i < hi; i += 256) {
        unsigned b = ((unsigned)dstp[i] << 8) / Nt;
        atomicAdd(&hist[b], 1);
    }
    __syncthreads();
    gb[tid] = hist[tid] ? atomicAdd(&bcursor[k * 256 + tid], hist[tid]) : 0;
    cur[tid] = 0;
    __syncthreads();
    for (int i = base + tid; i < hi; i += 256) {
        int src = srcp[i], dst = dstp[i];
        unsigned b = ((unsigned)dst << 8) / Nt;
        int r = atomicAdd(&cur[b], 1);
        binned[(size_t)gb[b] + r] = make_int2(src, dst);
    }
}

__global__ __launch_bounds__(256) void fine_fill(const int2* __restrict__ binned,
                                                 const int* __restrict__ bbase,
                                                 int* __restrict__ rowstart,
                                                 int* __restrict__ ssrc) {
    __shared__ int rcnt[784];
    __shared__ int excl[784];
    __shared__ int scur[784];
    __shared__ int sb[256];
    int k = blockIdx.y, b = blockIdx.x, tid = threadIdx.x;
    int Nt = d_NC[k % 3];
    int segb = d_SEGB[k];
    int row_lo = (b * Nt + 255) >> 8;
    int row_hi = ((b + 1) * Nt + 255) >> 8;
    int nrows = row_hi - row_lo;
    int ebase = bbase[k * 256 + b];
    int eend  = bbase[k * 256 + b + 1];
    for (int i = tid; i < nrows; i += 256) rcnt[i] = 0;
    __syncthreads();
    for (int e = ebase + tid; e < eend; e += 256)
        atomicAdd(&rcnt[binned[e].y - row_lo], 1);
    __syncthreads();
    int stride = (nrows + 255) >> 8;
    int lo = tid * stride;
    int hi2 = min(lo + stride, nrows);
    int s = 0;
    for (int i = lo; i < hi2; ++i) s += rcnt[i];
    sb[tid] = s; __syncthreads();
    int v = s;
    for (int off = 1; off < 256; off <<= 1) {
        int u = (tid >= off) ? sb[tid - off] : 0;
        __syncthreads();
        sb[tid] += u;
        __syncthreads();
    }
    int pre = sb[tid] - v;
    for (int i = lo; i < hi2; ++i) {
        excl[i] = pre;
        scur[i] = pre;
        pre += rcnt[i];
    }
    __syncthreads();
    for (int i = tid; i < nrows; i += 256)
        rowstart[segb + row_lo + i] = ebase + excl[i];
    if (k == 8 && b == 255 && tid == 0) rowstart[TOT_ROWS] = eend;
    for (int e = ebase + tid; e < eend; e += 256) {
        int2 ed = binned[e];
        int r = atomicAdd(&scur[ed.y - row_lo], 1);
        ssrc[ebase + r] = ed.x;
    }
}

// ----------------------------------------------------- aggregate, all 9 k
__global__ __launch_bounds__(256) void aggregate_all(const f16* __restrict__ x16,
                                                     const int* __restrict__ rowstart,
                                                     const int* __restrict__ ssrc,
                                                     char* __restrict__ slabs,
                                                     const float* __restrict__ eps9) {
    __shared__ float part[4][128];
    int g = blockIdx.x;
    int k = 0;
    #pragma unroll
    for (int j = 1; j < 9; ++j) if (g >= d_AOFF[j]) k = j;
    int b = g - d_AOFF[k];
    int s = k / 3, t = k % 3;
    int N = d_NC[t];
    const int* rs = rowstart + d_SEGB[k];
    const f16* xsrc = x16 + (size_t)d_XB[s] * D;
    const f16* xt   = x16 + (size_t)d_XB[t] * D;
    char* slab = slabs + (size_t)s * SLABSZ + (size_t)d_XB[t] * 256;
    float epsv = 1.0f + eps9[k];
    int tid  = threadIdx.x;
    int lane = tid & 63;
    int w    = tid >> 6;
    int grp  = lane >> 4;
    int cs   = lane & 15;

    if (t != 1) {
        int row = (b << 4) + (tid >> 4);
        if (row >= N) return;          // exact grids; no barrier in this path
        int e0 = rs[row], e1 = rs[row + 1];
        f16x8 xv = ((const f16x8*)(xt + (size_t)row * D))[cs];
        float acc[8];
        #pragma unroll
        for (int j = 0; j < 8; ++j) acc[j] = epsv * (float)xv[j];
        int e = e0;
        for (; e + 3 < e1; e += 4) {
            int s0 = ssrc[e], s1 = ssrc[e + 1], s2 = ssrc[e + 2], s3 = ssrc[e + 3];
            f16x8 v0 = ((const f16x8*)(xsrc + (size_t)s0 * D))[cs];
            f16x8 v1 = ((const f16x8*)(xsrc + (size_t)s1 * D))[cs];
            f16x8 v2 = ((const f16x8*)(xsrc + (size_t)s2 * D))[cs];
            f16x8 v3 = ((const f16x8*)(xsrc + (size_t)s3 * D))[cs];
            #pragma unroll
            for (int j = 0; j < 8; ++j)
                acc[j] += ((float)v0[j] + (float)v1[j]) + ((float)v2[j] + (float)v3[j]);
        }
        if (e + 1 < e1) {
            int s0 = ssrc[e], s1 = ssrc[e + 1];
            f16x8 v0 = ((const f16x8*)(xsrc + (size_t)s0 * D))[cs];
            f16x8 v1 = ((const f16x8*)(xsrc + (size_t)s1 * D))[cs];
            #pragma unroll
            for (int j = 0; j < 8; ++j) acc[j] += (float)v0[j] + (float)v1[j];
            e += 2;
        }
        if (e < e1) {
            int s0 = ssrc[e];
            f16x8 v0 = ((const f16x8*)(xsrc + (size_t)s0 * D))[cs];
            #pragma unroll
            for (int j = 0; j < 8; ++j) acc[j] += (float)v0[j];
        }
        f16x8 h;
        #pragma unroll
        for (int j = 0; j < 8; ++j) h[j] = (f16)acc[j];
        ((f16x8*)(slab + (size_t)row * 256))[cs] = h;
    } else {
        int row = b;
        int estart = w * 4 + grp, estep = 16;
        float acc[8];
        #pragma unroll
        for (int j = 0; j < 8; ++j) acc[j] = 0.f;
        int e1 = rs[row + 1];
        int e  = rs[row] + estart;
        for (; e + 3 * estep < e1; e += 4 * estep) {
            int s0 = ssrc[e], s1 = ssrc[e + estep], s2 = ssrc[e + 2 * estep], s3 = ssrc[e + 3 * estep];
            f16x8 v0 = ((const f16x8*)(xsrc + (size_t)s0 * D))[cs];
            f16x8 v1 = ((const f16x8*)(xsrc + (size_t)s1 * D))[cs];
            f16x8 v2 = ((const f16x8*)(xsrc + (size_t)s2 * D))[cs];
            f16x8 v3 = ((const f16x8*)(xsrc + (size_t)s3 * D))[cs];
            #pragma unroll
            for (int j = 0; j < 8; ++j)
                acc[j] += ((float)v0[j] + (float)v1[j]) + ((float)v2[j] + (float)v3[j]);
        }
        for (; e < e1; e += estep) {
            int s0 = ssrc[e];
            f16x8 v0 = ((const f16x8*)(xsrc + (size_t)s0 * D))[cs];
            #pragma unroll
            for (int j = 0; j < 8; ++j) acc[j] += (float)v0[j];
        }
        #pragma unroll
        for (int j = 0; j < 8; ++j) {
            acc[j] += __shfl_xor(acc[j], 16);
            acc[j] += __shfl_xor(acc[j], 32);
        }
        if (lane < 16) {
            #pragma unroll
            for (int j = 0; j < 8; ++j) part[w][cs * 8 + j] = acc[j];
        }
        __syncthreads();
        if (w == 0 && lane < 16) {
            f16x8 xv = ((const f16x8*)(xt + (size_t)row * D))[cs];
            f16x8 h;
            #pragma unroll
            for (int j = 0; j < 8; ++j) {
                float v = (part[0][cs*8+j] + part[1][cs*8+j]) + (part[2][cs*8+j] + part[3][cs*8+j]);
                h[j] = (f16)(v + epsv * (float)xv[j]);
            }
            ((f16x8*)(slab + (size_t)row * 256))[cs] = h;
        }
    }
}

// -------------------------------------------------------------- layer-1 GEMM
__global__ __launch_bounds__(256) void gemm_l1(char* __restrict__ slabs,
                                               const f16* __restrict__ Wth,
                                               const float* __restrict__ bias,
                                               float* __restrict__ partials) {
    __shared__ alignas(16) char atile[64 * 256];
    __shared__ float wst[4][256];
    const int tid  = threadIdx.x;
    const int lane = tid & 63;
    const int w    = tid >> 6;
    const int s    = blockIdx.y;
    int t, tl;
    tile_map64(blockIdx.x, t, tl);
    const int N = d_NC[t];
    const int row0 = tl * 64;
    char* slab = slabs + (size_t)s * SLABSZ + (size_t)d_XB[t] * 256;

    #pragma unroll
    for (int p = 0; p < 4; ++p) {
        int r  = p * 16 + (tid >> 4);
        int c8 = tid & 15;
        int row = row0 + r;
        if (row >= N) row = N - 1;   // clamp: garbage masked in epilogue
        const char* src = slab + (size_t)row * 256 + (unsigned)((c8 * 16) ^ ((r & 7) << 4));
        __builtin_amdgcn_global_load_lds(
            (const __attribute__((address_space(1))) void*)src,
            (__attribute__((address_space(3))) void*)(atile + p * 4096 + w * 1024),
            16, 0, 0);
    }
    __syncthreads();

    const f16* Wt = Wth + (size_t)s * 16384;
    f32x4 acc0[8];
    #pragma unroll
    for (int ct = 0; ct < 8; ++ct) acc0[ct] = (f32x4){0.f, 0.f, 0.f, 0.f};
    const int arow = (w << 4) + (lane & 15);
    const int kq = (lane >> 4) * 8;
    #pragma unroll
    for (int ks = 0; ks < 4; ++ks) {
        f16x8 af = *(const f16x8*)(atile + a_swz(arow, (ks * 32 + kq) * 2));
        #pragma unroll
        for (int ct = 0; ct < 8; ++ct) {
            f16x8 bf = *(const f16x8*)(Wt + (size_t)(ct * 16 + (lane & 15)) * D + ks * 32 + kq);
            acc0[ct] = __builtin_amdgcn_mfma_f32_16x16x32_f16(af, bf, acc0[ct], 0, 0, 0);
        }
    }

    const int col_lo = lane & 15;
    const int lrb0 = (w << 4) + ((lane >> 4) << 2);
    #pragma unroll
    for (int ct = 0; ct < 8; ++ct) {
        int col = ct * 16 + col_lo;
        float bv = bias[s * D + col];
        float s_ = 0.f, q_ = 0.f;
        #pragma unroll
        for (int r = 0; r < 4; ++r) {
            int lrow = lrb0 + r;
            float val = acc0[ct][r] + bv;
            if (row0 + lrow < N) { s_ += val; q_ += val * val; }
            *(f16*)(atile + a_swz(lrow, col * 2)) = (f16)val;
        }
        s_ += __shfl_xor(s_, 16); q_ += __shfl_xor(q_, 16);
        s_ += __shfl_xor(s_, 32); q_ += __shfl_xor(q_, 32);
        if (lane < 16) { wst[w][col] = s_; wst[w][128 + col] = q_; }
    }
    __syncthreads();

    #pragma unroll
    for (int p = 0; p < 4; ++p) {
        int r  = p * 16 + (tid >> 4);
        int c8 = tid & 15;
        int row = row0 + r;
        if (row < N)
            *(f16x8*)(slab + (size_t)row * 256 + c8 * 16) = *(const f16x8*)(atile + a_swz(r, c8 * 16));
    }
    float pv = wst[0][tid] + wst[1][tid] + wst[2][tid] + wst[3][tid];
    partials[((size_t)blockIdx.x * 3 + s) * 256 + tid] = pv;
}

// -------------------------------------------------------------- layer-2 GEMM
// grid (3485, 3). 64-row tiles. NOW: z1 staged raw via global_load_lds
// (pre-swizzled source, async direct-to-LDS — no VGPR round-trip); the BN1
// affine+relu transform is applied at MFMA A-fragment READ time (each z1
// element is consumed exactly once, by its owning wave). Numerics identical
// to the reg-staged version (f16 z1 -> f32 transform).
__global__ __launch_bounds__(256) void gemm_l2(char* __restrict__ slabs,
                                               const f16* __restrict__ Wth2,
                                               const float* __restrict__ bias,
                                               const float* __restrict__ affa,
                                               const float* __restrict__ affc,
                                               float* __restrict__ partials) {
    __shared__ alignas(16) char atile[64 * 256];
    __shared__ float wst[4][256];
    const int tid  = threadIdx.x;
    const int lane = tid & 63;
    const int w    = tid >> 6;
    const int s    = blockIdx.y;
    int t, tl;
    tile_map64(blockIdx.x, t, tl);
    const int N = d_NC[t];
    const int row0 = tl * 64;
    const int k = s * 3 + t;
    char* slab = slabs + (size_t)s * SLABSZ + (size_t)d_XB[t] * 256;

    #pragma unroll
    for (int p = 0; p < 4; ++p) {
        int r  = p * 16 + (tid >> 4);
        int c8 = tid & 15;
        int row = row0 + r;
        if (row >= N) row = N - 1;   // clamp: garbage rows feed garbage output rows only
        const char* src = slab + (size_t)row * 256 + (unsigned)((c8 * 16) ^ ((r & 7) << 4));
        __builtin_amdgcn_global_load_lds(
            (const __attribute__((address_space(1))) void*)src,
            (__attribute__((address_space(3))) void*)(atile + p * 4096 + w * 1024),
            16, 0, 0);
    }
    __syncthreads();   // drain vmcnt: global_load_lds deposits via VMEM

    const f16* Wt = Wth2 + (size_t)s * 16384;
    f32x4 acc0[8];
    #pragma unroll
    for (int ct = 0; ct < 8; ++ct) acc0[ct] = (f32x4){0.f, 0.f, 0.f, 0.f};
    const int arow = (w << 4) + (lane & 15);
    const int kq = (lane >> 4) * 8;
    #pragma unroll
    for (int ks = 0; ks < 4; ++ks) {
        // transform-on-read: raw z1 frag -> (z1*a + c), relu -> f16 A-frag
        const int cb = ks * 32 + kq;   // this lane's 8 k-columns
        f32x4 a0 = *(const f32x4*)(affa + k * 128 + cb);
        f32x4 a1 = *(const f32x4*)(affa + k * 128 + cb + 4);
        f32x4 c0 = *(const f32x4*)(affc + k * 128 + cb);
        f32x4 c1 = *(const f32x4*)(affc + k * 128 + cb + 4);
        f16x8 raw = *(const f16x8*)(atile + a_swz(arow, cb * 2));
        f16x8 af;
        #pragma unroll
        for (int j = 0; j < 4; ++j) {
            float t0 = (float)raw[j] * a0[j] + c0[j];
            float t1 = (float)raw[4 + j] * a1[j] + c1[j];
            af[j]     = (f16)(t0 > 0.f ? t0 : 0.f);
            af[4 + j] = (f16)(t1 > 0.f ? t1 : 0.f);
        }
        #pragma unroll
        for (int ct = 0; ct < 8; ++ct) {
            f16x8 bf = *(const f16x8*)(Wt + (size_t)(ct * 16 + (lane & 15)) * D + ks * 32 + kq);
            acc0[ct] = __builtin_amdgcn_mfma_f32_16x16x32_f16(af, bf, acc0[ct], 0, 0, 0);
        }
    }

    // epilogue: z2 overwrites atile (wave-private rows: each wave's A-frags
    // came only from its own rows, all consumed above)
    const int col_lo = lane & 15;
    const int lrb0 = (w << 4) + ((lane >> 4) << 2);
    #pragma unroll
    for (int ct = 0; ct < 8; ++ct) {
        int col = ct * 16 + col_lo;
        float bv = bias[s * D + col];
        float s_ = 0.f, q_ = 0.f;
        #pragma unroll
        for (int r = 0; r < 4; ++r) {
            int lrow = lrb0 + r;
            float val = acc0[ct][r] + bv;
            if (row0 + lrow < N) { s_ += val; q_ += val * val; }
            *(f16*)(atile + a_swz(lrow, col * 2)) = (f16)val;
        }
        s_ += __shfl_xor(s_, 16); q_ += __shfl_xor(q_, 16);
        s_ += __shfl_xor(s_, 32); q_ += __shfl_xor(q_, 32);
        if (lane < 16) { wst[w][col] = s_; wst[w][128 + col] = q_; }
    }
    __syncthreads();

    #pragma unroll
    for (int p = 0; p < 4; ++p) {
        int r = p * 16 + (tid >> 4);
        int c8 = tid & 15;
        int row = row0 + r;
        if (row < N)
            *(f16x8*)(slab + (size_t)row * 256 + c8 * 16) = *(const f16x8*)(atile + a_swz(r, c8 * 16));
    }
    float pv = wst[0][tid] + wst[1][tid] + wst[2][tid] + wst[3][tid];
    partials[((size_t)blockIdx.x * 3 + s) * 256 + tid] = pv;
}

// ----------------------------------------------------------- stats reduction
__global__ void bn_reduce(const float* __restrict__ partials,
                          float* __restrict__ partial2) {
    int k = blockIdx.y, tid = threadIdx.x;
    int s = k / 3, t = k % 3;
    int lo = d_T64LO[t], hi = d_T64HI[t];
    float v = 0.f;
    for (int b = lo + blockIdx.x; b < hi; b += NR64)
        v += partials[((size_t)b * 3 + s) * 256 + tid];
    partial2[((size_t)k * NR64 + blockIdx.x) * 256 + tid] = v;
}

__global__ void bn_params(const float* __restrict__ partial2,
                          const float* __restrict__ g, const float* __restrict__ be,
                          float* __restrict__ affa, float* __restrict__ affc) {
    __shared__ float red[256];
    int k = blockIdx.x, tid = threadIdx.x;
    int s = k / 3, t = k % 3;
    float v = 0.f;
    #pragma unroll 4
    for (int b = 0; b < NR64; ++b)
        v += partial2[((size_t)k * NR64 + b) * 256 + tid];
    red[tid] = v;
    __syncthreads();
    if (tid < 128) {
        float sm = red[tid], q = red[128 + tid];
        float n = (float)d_NC[t];
        float mean = sm / n;
        float var  = q / n - mean * mean;
        float a = g[s * D + tid] * rsqrtf(var + 1e-5f);
        affa[k * 128 + tid] = a;
        affc[k * 128 + tid] = be[s * D + tid] - mean * a;
    }
}

// -------------------------------------------------- final accum, all rows
__global__ __launch_bounds__(256) void accum_all(const char* __restrict__ slabs,
                                                 const float* __restrict__ affa,
                                                 const float* __restrict__ affc,
                                                 float* __restrict__ outp) {
    const int total = 223000 * 16;
    for (int i = blockIdx.x * 256 + threadIdx.x; i < total; i += gridDim.x * 256) {
        int row = i >> 4;
        int c8  = i & 15;
        int t = (row < 200000) ? 0 : (row < 203000) ? 1 : 2;
        f32x4 o0 = {0.f, 0.f, 0.f, 0.f}, o1 = {0.f, 0.f, 0.f, 0.f};
        #pragma unroll
        for (int s = 0; s < 3; ++s) {
            int k = s * 3 + t;
            f16x8 z = ((const f16x8*)(slabs + (size_t)s * SLABSZ + (size_t)row * 256))[c8];
            f32x4 a0 = ((const f32x4*)(affa + k * 128))[c8 * 2];
            f32x4 a1 = ((const f32x4*)(affa + k * 128))[c8 * 2 + 1];
            f32x4 c0 = ((const f32x4*)(affc + k * 128))[c8 * 2];
            f32x4 c1 = ((const f32x4*)(affc + k * 128))[c8 * 2 + 1];
            #pragma unroll
            for (int j = 0; j < 4; ++j) {
                float t0 = (float)z[j] * a0[j] + c0[j];
                float t1 = (float)z[4 + j] * a1[j] + c1[j];
                o0[j] += t0 > 0.f ? t0 : 0.f;
                o1[j] += t1 > 0.f ? t1 : 0.f;
            }
        }
        ((f32x4*)(outp + (size_t)row * D))[c8 * 2]     = o0;
        ((f32x4*)(outp + (size_t)row * D))[c8 * 2 + 1] = o1;
    }
}

extern "C" void kernel_launch(void* const* d_in, const int* in_sizes, int n_in,
                              void* d_out, int out_size, void* d_ws, size_t ws_size,
                              hipStream_t stream) {
    const float* x0  = (const float*)d_in[0];
    const float* x1  = (const float*)d_in[1];
    const float* x2  = (const float*)d_in[2];
    const int*   ei  = (const int*)d_in[3];
    const float* W1  = (const float*)d_in[4];
    const float* b1  = (const float*)d_in[5];
    const float* g1  = (const float*)d_in[6];
    const float* be1 = (const float*)d_in[7];
    const float* W2  = (const float*)d_in[8];
    const float* b2  = (const float*)d_in[9];
    const float* g2  = (const float*)d_in[10];
    const float* be2 = (const float*)d_in[11];
    const float* eps9 = (const float*)d_in[12];
    float* outp = (float*)d_out;

    char* ws = (char*)d_ws;
    size_t off = 0;
    char* slabs = ws;                 off += 3 * SLABSZ;                   // 171.3 MB
    int2* binned = (int2*)slabs;      // 36 MB alias, consumed before slabs written
    f16* x16    = (f16*)(ws + off);   off += SLABSZ;                       // 57.1 MB
    int* ssrc   = (int*)(ws + off);   off += (size_t)9 * E_PER * 4;        // 18 MB
    int* rowstart = (int*)(ws + off); off += (size_t)(TOT_ROWS + 2) * 4;
    off = (off + 255) & ~(size_t)255;
    int* bcnt   = (int*)(ws + off);   off += 2308 * 4;
    int* bbase  = (int*)(ws + off);   off += 2308 * 4;
    int* bcursor= (int*)(ws + off);   off += 2308 * 4;
    off = (off + 255) & ~(size_t)255;
    float* partials = (float*)(ws + off); off += (size_t)3485 * 3 * 256 * 4;
    float* partial2 = (float*)(ws + off); off += (size_t)9 * NR64 * 256 * 4;
    float* aff1a = (float*)(ws + off); off += 9 * 128 * 4;
    float* aff1c = (float*)(ws + off); off += 9 * 128 * 4;
    float* aff2a = (float*)(ws + off); off += 9 * 128 * 4;
    float* aff2c = (float*)(ws + off); off += 9 * 128 * 4;
    f16* Wth = (f16*)(ws + off); off += (size_t)2 * 3 * 128 * 128 * sizeof(f16);

    // ---- setup
    precast<<<384, 256, 0, stream>>>(W1, W2, Wth);

    // ---- CSR build (pass 1 carries the x->f16 cast as a fused side job)
    hipMemsetAsync(bcnt, 0, 2308 * 4, stream);
    int nchunk = (E_PER + CH - 1) / CH;   // 123
    bucket_count<<<dim3(nchunk, 9), 256, 0, stream>>>(ei, bcnt, x0, x1, x2, x16);
    bucket_scan<<<1, 256, 0, stream>>>(bcnt, bbase, bcursor);
    bin_scatter<<<dim3(nchunk, 9), 256, 0, stream>>>(ei, bcursor, binned);
    fine_fill<<<dim3(256, 9), 256, 0, stream>>>(binned, bbase, rowstart, ssrc);

    // ---- aggregate all 9 (s,t) into slabs (folds (1+eps)*x_t)
    aggregate_all<<<50250, 256, 0, stream>>>(x16, rowstart, ssrc, slabs, eps9);

    gemm_l1<<<dim3(3485, 3), 256, 0, stream>>>(slabs, Wth, b1, partials);
    bn_reduce<<<dim3(NR64, 9), 256, 0, stream>>>(partials, partial2);
    bn_params<<<9, 256, 0, stream>>>(partial2, g1, be1, aff1a, aff1c);

    gemm_l2<<<dim3(3485, 3), 256, 0, stream>>>(slabs, Wth + 3 * 16384, b2,
                                               aff1a, aff1c, partials);
    bn_reduce<<<dim3(NR64, 9), 256, 0, stream>>>(partials, partial2);
    bn_params<<<9, 256, 0, stream>>>(partial2, g2, be2, aff2a, aff2c);

    accum_all<<<4096, 256, 0, stream>>>(slabs, aff2a, aff2c, outp);
}

// Round 21
// 781.329 us; speedup vs baseline: 1.0081x; 1.0081x over previous
//
#include <hip/hip_runtime.h>
#include <hip/hip_fp16.h>

#define D 128
#define E_PER 500000
#define TOT_ROWS 669000
#define CH 4096
#define NR64 64
#define SLABSZ ((size_t)223000 * 256)

typedef _Float16 f16;
typedef _Float16 f16x8 __attribute__((ext_vector_type(8)));
typedef _Float16 f16x4 __attribute__((ext_vector_type(4)));
typedef _Float16 f16x2 __attribute__((ext_vector_type(2)));
typedef float f32x4 __attribute__((ext_vector_type(4)));

// Per-edge-type row-segment bases in the concatenated CSR arrays (k = s*3 + t).
__device__ const int d_SEGB[9] = {0, 200000, 203000, 223000, 423000, 426000,
                                  446000, 646000, 649000};
__device__ const int d_XB[3] = {0, 200000, 203000};
__device__ const int d_NC[3] = {200000, 3000, 20000};
// gemm tile ranges per t (64-row tiles): t0 3125, t1 47, t2 313
__device__ const int d_T64LO[3] = {0, 3125, 3172};
__device__ const int d_T64HI[3] = {3125, 3172, 3485};
// aggregate block offsets per k: t0/t2 = 16 rows/block (group-per-row);
// t1 = 1 row/block (16 edge slots)
__device__ const int d_AOFF[10] = {0, 12500, 15500, 16750, 29250, 32250,
                                   33500, 46000, 49000, 50250};

// XOR swizzle for the A tile in LDS (row stride 256B f16).
__device__ __forceinline__ unsigned a_swz(int row, int byteoff) {
    return (unsigned)(row * 256 + byteoff) ^ (unsigned)((row & 7) << 4);
}

// map global gemm tile (64-row) -> (t, local tile)
__device__ __forceinline__ void tile_map64(int g, int& t, int& tl) {
    if (g < 3125)      { t = 0; tl = g; }
    else if (g < 3172) { t = 1; tl = g - 3125; }
    else               { t = 2; tl = g - 3172; }
}

// ---------------------------------------------------------------- precast W^T
__global__ void precast(const float* __restrict__ W1,
                        const float* __restrict__ W2,
                        f16* __restrict__ Wth) {
    int i = blockIdx.x * 256 + threadIdx.x;
    if (i >= 2 * 3 * 128 * 128) return;
    int layer = i / 49152;
    int rem = i - layer * 49152;
    int s = rem / 16384;
    int r2 = rem & 16383;
    int kk = r2 >> 7;
    int c  = r2 & 127;
    const float* W = layer ? W2 : W1;
    Wth[(((size_t)layer * 3 + s) * 128 + c) * 128 + kk] = (f16)W[((size_t)s * 128 + kk) * 128 + c];
}

// ==================== CSR pass 1: bucket histogram + FUSED x->f16 cast
__global__ __launch_bounds__(256) void bucket_count(const int* __restrict__ ei,
                                                    int* __restrict__ bcnt,
                                                    const float* __restrict__ x0,
                                                    const float* __restrict__ x1,
                                                    const float* __restrict__ x2,
                                                    f16* __restrict__ y) {
    __shared__ int hist[256];
    int k = blockIdx.y, tid = threadIdx.x;
    const int* dstp = ei + (size_t)k * 2 * E_PER + E_PER;
    unsigned Nt = (unsigned)d_NC[k % 3];
    int base = blockIdx.x * CH;
    int hi = min(base + CH, E_PER);
    hist[tid] = 0;
    __syncthreads();
    for (int i = base + tid; i < hi; i += 256) {
        unsigned b = ((unsigned)dstp[i] << 8) / Nt;
        atomicAdd(&hist[b], 1);
    }
    __syncthreads();
    if (hist[tid]) atomicAdd(&bcnt[k * 256 + tid], hist[tid]);

    // ---- fused cast: grid-stride over all 223000*16 f16x8 slots
    const int nb = gridDim.x * gridDim.y;                 // 1107
    const int bid = blockIdx.y * gridDim.x + blockIdx.x;
    const int total = 223000 * 16;
    for (int i = bid * 256 + tid; i < total; i += nb * 256) {
        int row = i >> 4, c8 = i & 15;
        const float* src;
        if (row < 200000)      src = x0 + (size_t)row * D;
        else if (row < 203000) src = x1 + (size_t)(row - 200000) * D;
        else                   src = x2 + (size_t)(row - 203000) * D;
        f32x4 v0 = ((const f32x4*)src)[c8 * 2];
        f32x4 v1 = ((const f32x4*)src)[c8 * 2 + 1];
        f16x8 h;
        #pragma unroll
        for (int j = 0; j < 4; ++j) { h[j] = (f16)v0[j]; h[4 + j] = (f16)v1[j]; }
        ((f16x8*)(y + (size_t)row * D))[c8] = h;
    }
}

__global__ void bucket_scan(const int* __restrict__ bcnt,
                            int* __restrict__ bbase, int* __restrict__ bcursor) {
    __shared__ int sb[256];
    int t = threadIdx.x;
    int loc[9];
    int s = 0;
    #pragma unroll
    for (int j = 0; j < 9; ++j) { loc[j] = bcnt[t * 9 + j]; s += loc[j]; }
    sb[t] = s; __syncthreads();
    int v = s;
    for (int off = 1; off < 256; off <<= 1) {
        int u = (t >= off) ? sb[t - off] : 0;
        __syncthreads();
        sb[t] += u;
        __syncthreads();
    }
    int pre = sb[t] - v;
    #pragma unroll
    for (int j = 0; j < 9; ++j) {
        bbase[t * 9 + j] = pre;
        bcursor[t * 9 + j] = pre;
        pre += loc[j];
    }
    if (t == 255) bbase[2304] = pre;
}

__global__ __launch_bounds__(256) void bin_scatter(const int* __restrict__ ei,
                                                   int* __restrict__ bcursor,
                                                   int2* __restrict__ binned) {
    __shared__ int hist[256], gb[256], cur[256];
    int k = blockIdx.y, tid = threadIdx.x;
    const int* srcp = ei + (size_t)k * 2 * E_PER;
    const int* dstp = srcp + E_PER;
    unsigned Nt = (unsigned)d_NC[k % 3];
    int base = blockIdx.x * CH;
    int hi = min(base + CH, E_PER);
    hist[tid] = 0;
    __syncthreads();
    for (int i = base + tid; i < hi; i += 256) {
        unsigned b = ((unsigned)dstp[i] << 8) / Nt;
        atomicAdd(&hist[b], 1);
    }
    __syncthreads();
    gb[tid] = hist[tid] ? atomicAdd(&bcursor[k * 256 + tid], hist[tid]) : 0;
    cur[tid] = 0;
    __syncthreads();
    for (int i = base + tid; i < hi; i += 256) {
        int src = srcp[i], dst = dstp[i];
        unsigned b = ((unsigned)dst << 8) / Nt;
        int r = atomicAdd(&cur[b], 1);
        binned[(size_t)gb[b] + r] = make_int2(src, dst);
    }
}

__global__ __launch_bounds__(256) void fine_fill(const int2* __restrict__ binned,
                                                 const int* __restrict__ bbase,
                                                 int* __restrict__ rowstart,
                                                 int* __restrict__ ssrc) {
    __shared__ int rcnt[784];
    __shared__ int excl[784];
    __shared__ int scur[784];
    __shared__ int sb[256];
    int k = blockIdx.y, b = blockIdx.x, tid = threadIdx.x;
    int Nt = d_NC[k % 3];
    int segb = d_SEGB[k];
    int row_lo = (b * Nt + 255) >> 8;
    int row_hi = ((b + 1) * Nt + 255) >> 8;
    int nrows = row_hi - row_lo;
    int ebase = bbase[k * 256 + b];
    int eend  = bbase[k * 256 + b + 1];
    for (int i = tid; i < nrows; i += 256) rcnt[i] = 0;
    __syncthreads();
    for (int e = ebase + tid; e < eend; e += 256)
        atomicAdd(&rcnt[binned[e].y - row_lo], 1);
    __syncthreads();
    int stride = (nrows + 255) >> 8;
    int lo = tid * stride;
    int hi2 = min(lo + stride, nrows);
    int s = 0;
    for (int i = lo; i < hi2; ++i) s += rcnt[i];
    sb[tid] = s; __syncthreads();
    int v = s;
    for (int off = 1; off < 256; off <<= 1) {
        int u = (tid >= off) ? sb[tid - off] : 0;
        __syncthreads();
        sb[tid] += u;
        __syncthreads();
    }
    int pre = sb[tid] - v;
    for (int i = lo; i < hi2; ++i) {
        excl[i] = pre;
        scur[i] = pre;
        pre += rcnt[i];
    }
    __syncthreads();
    for (int i = tid; i < nrows; i += 256)
        rowstart[segb + row_lo + i] = ebase + excl[i];
    if (k == 8 && b == 255 && tid == 0) rowstart[TOT_ROWS] = eend;
    for (int e = ebase + tid; e < eend; e += 256) {
        int2 ed = binned[e];
        int r = atomicAdd(&scur[ed.y - row_lo], 1);
        ssrc[ebase + r] = ed.x;
    }
}

// ----------------------------------------------------- aggregate, all 9 k
__global__ __launch_bounds__(256) void aggregate_all(const f16* __restrict__ x16,
                                                     const int* __restrict__ rowstart,
                                                     const int* __restrict__ ssrc,
                                                     char* __restrict__ slabs,
                                                     const float* __restrict__ eps9) {
    __shared__ float part[4][128];
    int g = blockIdx.x;
    int k = 0;
    #pragma unroll
    for (int j = 1; j < 9; ++j) if (g >= d_AOFF[j]) k = j;
    int b = g - d_AOFF[k];
    int s = k / 3, t = k % 3;
    int N = d_NC[t];
    const int* rs = rowstart + d_SEGB[k];
    const f16* xsrc = x16 + (size_t)d_XB[s] * D;
    const f16* xt   = x16 + (size_t)d_XB[t] * D;
    char* slab = slabs + (size_t)s * SLABSZ + (size_t)d_XB[t] * 256;
    float epsv = 1.0f + eps9[k];
    int tid  = threadIdx.x;
    int lane = tid & 63;
    int w    = tid >> 6;
    int grp  = lane >> 4;
    int cs   = lane & 15;

    if (t != 1) {
        int row = (b << 4) + (tid >> 4);
        if (row >= N) return;          // exact grids; no barrier in this path
        int e0 = rs[row], e1 = rs[row + 1];
        f16x8 xv = ((const f16x8*)(xt + (size_t)row * D))[cs];
        float acc[8];
        #pragma unroll
        for (int j = 0; j < 8; ++j) acc[j] = epsv * (float)xv[j];
        int e = e0;
        for (; e + 3 < e1; e += 4) {
            int s0 = ssrc[e], s1 = ssrc[e + 1], s2 = ssrc[e + 2], s3 = ssrc[e + 3];
            f16x8 v0 = ((const f16x8*)(xsrc + (size_t)s0 * D))[cs];
            f16x8 v1 = ((const f16x8*)(xsrc + (size_t)s1 * D))[cs];
            f16x8 v2 = ((const f16x8*)(xsrc + (size_t)s2 * D))[cs];
            f16x8 v3 = ((const f16x8*)(xsrc + (size_t)s3 * D))[cs];
            #pragma unroll
            for (int j = 0; j < 8; ++j)
                acc[j] += ((float)v0[j] + (float)v1[j]) + ((float)v2[j] + (float)v3[j]);
        }
        if (e + 1 < e1) {
            int s0 = ssrc[e], s1 = ssrc[e + 1];
            f16x8 v0 = ((const f16x8*)(xsrc + (size_t)s0 * D))[cs];
            f16x8 v1 = ((const f16x8*)(xsrc + (size_t)s1 * D))[cs];
            #pragma unroll
            for (int j = 0; j < 8; ++j) acc[j] += (float)v0[j] + (float)v1[j];
            e += 2;
        }
        if (e < e1) {
            int s0 = ssrc[e];
            f16x8 v0 = ((const f16x8*)(xsrc + (size_t)s0 * D))[cs];
            #pragma unroll
            for (int j = 0; j < 8; ++j) acc[j] += (float)v0[j];
        }
        f16x8 h;
        #pragma unroll
        for (int j = 0; j < 8; ++j) h[j] = (f16)acc[j];
        ((f16x8*)(slab + (size_t)row * 256))[cs] = h;
    } else {
        int row = b;
        int estart = w * 4 + grp, estep = 16;
        float acc[8];
        #pragma unroll
        for (int j = 0; j < 8; ++j) acc[j] = 0.f;
        int e1 = rs[row + 1];
        int e  = rs[row] + estart;
        for (; e + 3 * estep < e1; e += 4 * estep) {
            int s0 = ssrc[e], s1 = ssrc[e + estep], s2 = ssrc[e + 2 * estep], s3 = ssrc[e + 3 * estep];
            f16x8 v0 = ((const f16x8*)(xsrc + (size_t)s0 * D))[cs];
            f16x8 v1 = ((const f16x8*)(xsrc + (size_t)s1 * D))[cs];
            f16x8 v2 = ((const f16x8*)(xsrc + (size_t)s2 * D))[cs];
            f16x8 v3 = ((const f16x8*)(xsrc + (size_t)s3 * D))[cs];
            #pragma unroll
            for (int j = 0; j < 8; ++j)
                acc[j] += ((float)v0[j] + (float)v1[j]) + ((float)v2[j] + (float)v3[j]);
        }
        for (; e < e1; e += estep) {
            int s0 = ssrc[e];
            f16x8 v0 = ((const f16x8*)(xsrc + (size_t)s0 * D))[cs];
            #pragma unroll
            for (int j = 0; j < 8; ++j) acc[j] += (float)v0[j];
        }
        #pragma unroll
        for (int j = 0; j < 8; ++j) {
            acc[j] += __shfl_xor(acc[j], 16);
            acc[j] += __shfl_xor(acc[j], 32);
        }
        if (lane < 16) {
            #pragma unroll
            for (int j = 0; j < 8; ++j) part[w][cs * 8 + j] = acc[j];
        }
        __syncthreads();
        if (w == 0 && lane < 16) {
            f16x8 xv = ((const f16x8*)(xt + (size_t)row * D))[cs];
            f16x8 h;
            #pragma unroll
            for (int j = 0; j < 8; ++j) {
                float v = (part[0][cs*8+j] + part[1][cs*8+j]) + (part[2][cs*8+j] + part[3][cs*8+j]);
                h[j] = (f16)(v + epsv * (float)xv[j]);
            }
            ((f16x8*)(slab + (size_t)row * 256))[cs] = h;
        }
    }
}

// -------------------------------------------------------------- layer-1 GEMM
__global__ __launch_bounds__(256) void gemm_l1(char* __restrict__ slabs,
                                               const f16* __restrict__ Wth,
                                               const float* __restrict__ bias,
                                               float* __restrict__ partials) {
    __shared__ alignas(16) char atile[64 * 256];
    __shared__ float wst[4][256];
    const int tid  = threadIdx.x;
    const int lane = tid & 63;
    const int w    = tid >> 6;
    const int s    = blockIdx.y;
    int t, tl;
    tile_map64(blockIdx.x, t, tl);
    const int N = d_NC[t];
    const int row0 = tl * 64;
    char* slab = slabs + (size_t)s * SLABSZ + (size_t)d_XB[t] * 256;

    #pragma unroll
    for (int p = 0; p < 4; ++p) {
        int r  = p * 16 + (tid >> 4);
        int c8 = tid & 15;
        int row = row0 + r;
        if (row >= N) row = N - 1;   // clamp: garbage masked in epilogue
        const char* src = slab + (size_t)row * 256 + (unsigned)((c8 * 16) ^ ((r & 7) << 4));
        __builtin_amdgcn_global_load_lds(
            (const __attribute__((address_space(1))) void*)src,
            (__attribute__((address_space(3))) void*)(atile + p * 4096 + w * 1024),
            16, 0, 0);
    }
    __syncthreads();

    const f16* Wt = Wth + (size_t)s * 16384;
    f32x4 acc0[8];
    #pragma unroll
    for (int ct = 0; ct < 8; ++ct) acc0[ct] = (f32x4){0.f, 0.f, 0.f, 0.f};
    const int arow = (w << 4) + (lane & 15);
    const int kq = (lane >> 4) * 8;
    #pragma unroll
    for (int ks = 0; ks < 4; ++ks) {
        f16x8 af = *(const f16x8*)(atile + a_swz(arow, (ks * 32 + kq) * 2));
        #pragma unroll
        for (int ct = 0; ct < 8; ++ct) {
            f16x8 bf = *(const f16x8*)(Wt + (size_t)(ct * 16 + (lane & 15)) * D + ks * 32 + kq);
            acc0[ct] = __builtin_amdgcn_mfma_f32_16x16x32_f16(af, bf, acc0[ct], 0, 0, 0);
        }
    }

    const int col_lo = lane & 15;
    const int lrb0 = (w << 4) + ((lane >> 4) << 2);
    #pragma unroll
    for (int ct = 0; ct < 8; ++ct) {
        int col = ct * 16 + col_lo;
        float bv = bias[s * D + col];
        float s_ = 0.f, q_ = 0.f;
        #pragma unroll
        for (int r = 0; r < 4; ++r) {
            int lrow = lrb0 + r;
            float val = acc0[ct][r] + bv;
            if (row0 + lrow < N) { s_ += val; q_ += val * val; }
            *(f16*)(atile + a_swz(lrow, col * 2)) = (f16)val;
        }
        s_ += __shfl_xor(s_, 16); q_ += __shfl_xor(q_, 16);
        s_ += __shfl_xor(s_, 32); q_ += __shfl_xor(q_, 32);
        if (lane < 16) { wst[w][col] = s_; wst[w][128 + col] = q_; }
    }
    __syncthreads();

    #pragma unroll
    for (int p = 0; p < 4; ++p) {
        int r  = p * 16 + (tid >> 4);
        int c8 = tid & 15;
        int row = row0 + r;
        if (row < N)
            *(f16x8*)(slab + (size_t)row * 256 + c8 * 16) = *(const f16x8*)(atile + a_swz(r, c8 * 16));
    }
    float pv = wst[0][tid] + wst[1][tid] + wst[2][tid] + wst[3][tid];
    partials[((size_t)blockIdx.x * 3 + s) * 256 + tid] = pv;
}

// -------------------------------------------------------------- layer-2 GEMM
// grid (3485, 3). 64-row tiles, WAVE-PRIVATE reg-staged affine+relu transform
// (no barrier before MFMA — pure LDS path).
__global__ __launch_bounds__(256) void gemm_l2(char* __restrict__ slabs,
                                               const f16* __restrict__ Wth2,
                                               const float* __restrict__ bias,
                                               const float* __restrict__ affa,
                                               const float* __restrict__ affc,
                                               float* __restrict__ partials) {
    __shared__ alignas(16) char atile[64 * 256];
    __shared__ float wst[4][256];
    const int tid  = threadIdx.x;
    const int lane = tid & 63;
    const int w    = tid >> 6;
    const int s    = blockIdx.y;
    int t, tl;
    tile_map64(blockIdx.x, t, tl);
    const int N = d_NC[t];
    const int row0 = tl * 64;
    const int k = s * 3 + t;
    char* slab = slabs + (size_t)s * SLABSZ + (size_t)d_XB[t] * 256;
    const int c8 = lane & 15;
    const int g4 = lane >> 4;

    f32x4 a0 = ((const f32x4*)(affa + k * 128))[c8 * 2];
    f32x4 a1 = ((const f32x4*)(affa + k * 128))[c8 * 2 + 1];
    f32x4 c0 = ((const f32x4*)(affc + k * 128))[c8 * 2];
    f32x4 c1 = ((const f32x4*)(affc + k * 128))[c8 * 2 + 1];

    f16x8 zv[4];
    #pragma unroll
    for (int p = 0; p < 4; ++p) {
        int r = (w << 4) + p * 4 + g4;     // wave-private row
        int row = row0 + r;
        zv[p] = (row < N) ? ((const f16x8*)(slab + (size_t)row * 256))[c8]
                          : (f16x8){0, 0, 0, 0, 0, 0, 0, 0};
    }
    #pragma unroll
    for (int p = 0; p < 4; ++p) {
        int r = (w << 4) + p * 4 + g4;
        f16x8 hv;
        #pragma unroll
        for (int j = 0; j < 4; ++j) {
            float t0 = (float)zv[p][j] * a0[j] + c0[j];
            float t1 = (float)zv[p][4 + j] * a1[j] + c1[j];
            hv[j]     = (f16)(t0 > 0.f ? t0 : 0.f);
            hv[4 + j] = (f16)(t1 > 0.f ? t1 : 0.f);
        }
        *(f16x8*)(atile + a_swz(r, c8 * 16)) = hv;
    }
    // no barrier: MFMA reads only this wave's rows

    const f16* Wt = Wth2 + (size_t)s * 16384;
    f32x4 acc0[8];
    #pragma unroll
    for (int ct = 0; ct < 8; ++ct) acc0[ct] = (f32x4){0.f, 0.f, 0.f, 0.f};
    const int arow = (w << 4) + (lane & 15);
    const int kq = (lane >> 4) * 8;
    #pragma unroll
    for (int ks = 0; ks < 4; ++ks) {
        f16x8 af = *(const f16x8*)(atile + a_swz(arow, (ks * 32 + kq) * 2));
        #pragma unroll
        for (int ct = 0; ct < 8; ++ct) {
            f16x8 bf = *(const f16x8*)(Wt + (size_t)(ct * 16 + (lane & 15)) * D + ks * 32 + kq);
            acc0[ct] = __builtin_amdgcn_mfma_f32_16x16x32_f16(af, bf, acc0[ct], 0, 0, 0);
        }
    }

    const int col_lo = lane & 15;
    const int lrb0 = (w << 4) + ((lane >> 4) << 2);
    #pragma unroll
    for (int ct = 0; ct < 8; ++ct) {
        int col = ct * 16 + col_lo;
        float bv = bias[s * D + col];
        float s_ = 0.f, q_ = 0.f;
        #pragma unroll
        for (int r = 0; r < 4; ++r) {
            int lrow = lrb0 + r;
            float val = acc0[ct][r] + bv;
            if (row0 + lrow < N) { s_ += val; q_ += val * val; }
            *(f16*)(atile + a_swz(lrow, col * 2)) = (f16)val;
        }
        s_ += __shfl_xor(s_, 16); q_ += __shfl_xor(q_, 16);
        s_ += __shfl_xor(s_, 32); q_ += __shfl_xor(q_, 32);
        if (lane < 16) { wst[w][col] = s_; wst[w][128 + col] = q_; }
    }
    __syncthreads();

    #pragma unroll
    for (int p = 0; p < 4; ++p) {
        int r = p * 16 + (tid >> 4);
        int row = row0 + r;
        if (row < N)
            *(f16x8*)(slab + (size_t)row * 256 + (tid & 15) * 16) = *(const f16x8*)(atile + a_swz(r, (tid & 15) * 16));
    }
    float pv = wst[0][tid] + wst[1][tid] + wst[2][tid] + wst[3][tid];
    partials[((size_t)blockIdx.x * 3 + s) * 256 + tid] = pv;
}

// ----------------------------------------------------------- stats reduction
__global__ void bn_reduce(const float* __restrict__ partials,
                          float* __restrict__ partial2) {
    int k = blockIdx.y, tid = threadIdx.x;
    int s = k / 3, t = k % 3;
    int lo = d_T64LO[t], hi = d_T64HI[t];
    float v = 0.f;
    for (int b = lo + blockIdx.x; b < hi; b += NR64)
        v += partials[((size_t)b * 3 + s) * 256 + tid];
    partial2[((size_t)k * NR64 + blockIdx.x) * 256 + tid] = v;
}

__global__ void bn_params(const float* __restrict__ partial2,
                          const float* __restrict__ g, const float* __restrict__ be,
                          float* __restrict__ affa, float* __restrict__ affc) {
    __shared__ float red[256];
    int k = blockIdx.x, tid = threadIdx.x;
    int s = k / 3, t = k % 3;
    float v = 0.f;
    #pragma unroll 4
    for (int b = 0; b < NR64; ++b)
        v += partial2[((size_t)k * NR64 + b) * 256 + tid];
    red[tid] = v;
    __syncthreads();
    if (tid < 128) {
        float sm = red[tid], q = red[128 + tid];
        float n = (float)d_NC[t];
        float mean = sm / n;
        float var  = q / n - mean * mean;
        float a = g[s * D + tid] * rsqrtf(var + 1e-5f);
        affa[k * 128 + tid] = a;
        affc[k * 128 + tid] = be[s * D + tid] - mean * a;
    }
}

// -------------------------------------------------- final accum, all rows
__global__ __launch_bounds__(256) void accum_all(const char* __restrict__ slabs,
                                                 const float* __restrict__ affa,
                                                 const float* __restrict__ affc,
                                                 float* __restrict__ outp) {
    const int total = 223000 * 16;
    for (int i = blockIdx.x * 256 + threadIdx.x; i < total; i += gridDim.x * 256) {
        int row = i >> 4;
        int c8  = i & 15;
        int t = (row < 200000) ? 0 : (row < 203000) ? 1 : 2;
        f32x4 o0 = {0.f, 0.f, 0.f, 0.f}, o1 = {0.f, 0.f, 0.f, 0.f};
        #pragma unroll
        for (int s = 0; s < 3; ++s) {
            int k = s * 3 + t;
            f16x8 z = ((const f16x8*)(slabs + (size_t)s * SLABSZ + (size_t)row * 256))[c8];
            f32x4 a0 = ((const f32x4*)(affa + k * 128))[c8 * 2];
            f32x4 a1 = ((const f32x4*)(affa + k * 128))[c8 * 2 + 1];
            f32x4 c0 = ((const f32x4*)(affc + k * 128))[c8 * 2];
            f32x4 c1 = ((const f32x4*)(affc + k * 128))[c8 * 2 + 1];
            #pragma unroll
            for (int j = 0; j < 4; ++j) {
                float t0 = (float)z[j] * a0[j] + c0[j];
                float t1 = (float)z[4 + j] * a1[j] + c1[j];
                o0[j] += t0 > 0.f ? t0 : 0.f;
                o1[j] += t1 > 0.f ? t1 : 0.f;
            }
        }
        ((f32x4*)(outp + (size_t)row * D))[c8 * 2]     = o0;
        ((f32x4*)(outp + (size_t)row * D))[c8 * 2 + 1] = o1;
    }
}

extern "C" void kernel_launch(void* const* d_in, const int* in_sizes, int n_in,
                              void* d_out, int out_size, void* d_ws, size_t ws_size,
                              hipStream_t stream) {
    const float* x0  = (const float*)d_in[0];
    const float* x1  = (const float*)d_in[1];
    const float* x2  = (const float*)d_in[2];
    const int*   ei  = (const int*)d_in[3];
    const float* W1  = (const float*)d_in[4];
    const float* b1  = (const float*)d_in[5];
    const float* g1  = (const float*)d_in[6];
    const float* be1 = (const float*)d_in[7];
    const float* W2  = (const float*)d_in[8];
    const float* b2  = (const float*)d_in[9];
    const float* g2  = (const float*)d_in[10];
    const float* be2 = (const float*)d_in[11];
    const float* eps9 = (const float*)d_in[12];
    float* outp = (float*)d_out;

    char* ws = (char*)d_ws;
    size_t off = 0;
    char* slabs = ws;                 off += 3 * SLABSZ;                   // 171.3 MB
    int2* binned = (int2*)slabs;      // 36 MB alias, consumed before slabs written
    f16* x16    = (f16*)(ws + off);   off += SLABSZ;                       // 57.1 MB
    int* ssrc   = (int*)(ws + off);   off += (size_t)9 * E_PER * 4;        // 18 MB
    int* rowstart = (int*)(ws + off); off += (size_t)(TOT_ROWS + 2) * 4;
    off = (off + 255) & ~(size_t)255;
    int* bcnt   = (int*)(ws + off);   off += 2308 * 4;
    int* bbase  = (int*)(ws + off);   off += 2308 * 4;
    int* bcursor= (int*)(ws + off);   off += 2308 * 4;
    off = (off + 255) & ~(size_t)255;
    float* partials = (float*)(ws + off); off += (size_t)3485 * 3 * 256 * 4;
    float* partial2 = (float*)(ws + off); off += (size_t)9 * NR64 * 256 * 4;
    float* aff1a = (float*)(ws + off); off += 9 * 128 * 4;
    float* aff1c = (float*)(ws + off); off += 9 * 128 * 4;
    float* aff2a = (float*)(ws + off); off += 9 * 128 * 4;
    float* aff2c = (float*)(ws + off); off += 9 * 128 * 4;
    f16* Wth = (f16*)(ws + off); off += (size_t)2 * 3 * 128 * 128 * sizeof(f16);

    // ---- setup
    precast<<<384, 256, 0, stream>>>(W1, W2, Wth);

    // ---- CSR build (pass 1 carries the x->f16 cast as a fused side job)
    hipMemsetAsync(bcnt, 0, 2308 * 4, stream);
    int nchunk = (E_PER + CH - 1) / CH;   // 123
    bucket_count<<<dim3(nchunk, 9), 256, 0, stream>>>(ei, bcnt, x0, x1, x2, x16);
    bucket_scan<<<1, 256, 0, stream>>>(bcnt, bbase, bcursor);
    bin_scatter<<<dim3(nchunk, 9), 256, 0, stream>>>(ei, bcursor, binned);
    fine_fill<<<dim3(256, 9), 256, 0, stream>>>(binned, bbase, rowstart, ssrc);

    // ---- aggregate all 9 (s,t) into slabs (folds (1+eps)*x_t)
    aggregate_all<<<50250, 256, 0, stream>>>(x16, rowstart, ssrc, slabs, eps9);

    gemm_l1<<<dim3(3485, 3), 256, 0, stream>>>(slabs, Wth, b1, partials);
    bn_reduce<<<dim3(NR64, 9), 256, 0, stream>>>(partials, partial2);
    bn_params<<<9, 256, 0, stream>>>(partial2, g1, be1, aff1a, aff1c);

    gemm_l2<<<dim3(3485, 3), 256, 0, stream>>>(slabs, Wth + 3 * 16384, b2,
                                               aff1a, aff1c, partials);
    bn_reduce<<<dim3(NR64, 9), 256, 0, stream>>>(partials, partial2);
    bn_params<<<9, 256, 0, stream>>>(partial2, g2, be2, aff2a, aff2c);

    accum_all<<<4096, 256, 0, stream>>>(slabs, aff2a, aff2c, outp);
}

// Round 22
// 647.148 us; speedup vs baseline: 1.2171x; 1.2073x over previous
//
#include <hip/hip_runtime.h>
#include <hip/hip_fp16.h>

#define D 128
#define E_PER 500000
#define TOT_ROWS 669000
#define CH 4096
#define NR64 64
#define SLABSZ ((size_t)223000 * 256)

typedef _Float16 f16;
typedef _Float16 f16x8 __attribute__((ext_vector_type(8)));
typedef _Float16 f16x4 __attribute__((ext_vector_type(4)));
typedef _Float16 f16x2 __attribute__((ext_vector_type(2)));
typedef float f32x4 __attribute__((ext_vector_type(4)));

// Per-edge-type row-segment bases in the concatenated CSR arrays (k = s*3 + t).
__device__ const int d_SEGB[9] = {0, 200000, 203000, 223000, 423000, 426000,
                                  446000, 646000, 649000};
__device__ const int d_XB[3] = {0, 200000, 203000};
__device__ const int d_NC[3] = {200000, 3000, 20000};
// gemm tile ranges per t (128-row tiles): t0 1563, t1 24, t2 157
__device__ const int d_TLO[3] = {0, 1563, 1587};
__device__ const int d_THI[3] = {1563, 1587, 1744};
// aggregate block offsets per k: t0/t2 = 16 rows/block (group-per-row);
// t1 = 1 row/block (16 edge slots)
__device__ const int d_AOFF[10] = {0, 12500, 15500, 16750, 29250, 32250,
                                   33500, 46000, 49000, 50250};

// XOR swizzle for the A tile in LDS (row stride 256B f16).
__device__ __forceinline__ unsigned a_swz(int row, int byteoff) {
    return (unsigned)(row * 256 + byteoff) ^ (unsigned)((row & 7) << 4);
}

// map global gemm tile (128-row) -> (t, local tile)
__device__ __forceinline__ void tile_map(int g, int& t, int& tl) {
    if (g < 1563)      { t = 0; tl = g; }
    else if (g < 1587) { t = 1; tl = g - 1563; }
    else               { t = 2; tl = g - 1587; }
}

// ---------------------------------------------------------------- precast W^T
__global__ void precast(const float* __restrict__ W1,
                        const float* __restrict__ W2,
                        f16* __restrict__ Wth) {
    int i = blockIdx.x * 256 + threadIdx.x;
    if (i >= 2 * 3 * 128 * 128) return;
    int layer = i / 49152;
    int rem = i - layer * 49152;
    int s = rem / 16384;
    int r2 = rem & 16383;
    int kk = r2 >> 7;
    int c  = r2 & 127;
    const float* W = layer ? W2 : W1;
    Wth[(((size_t)layer * 3 + s) * 128 + c) * 128 + kk] = (f16)W[((size_t)s * 128 + kk) * 128 + c];
}

// ==================== CSR pass 1: bucket histogram + FUSED x->f16 cast
__global__ __launch_bounds__(256) void bucket_count(const int* __restrict__ ei,
                                                    int* __restrict__ bcnt,
                                                    const float* __restrict__ x0,
                                                    const float* __restrict__ x1,
                                                    const float* __restrict__ x2,
                                                    f16* __restrict__ y) {
    __shared__ int hist[256];
    int k = blockIdx.y, tid = threadIdx.x;
    const int* dstp = ei + (size_t)k * 2 * E_PER + E_PER;
    unsigned Nt = (unsigned)d_NC[k % 3];
    int base = blockIdx.x * CH;
    int hi = min(base + CH, E_PER);
    hist[tid] = 0;
    __syncthreads();
    for (int i = base + tid; i < hi; i += 256) {
        unsigned b = ((unsigned)dstp[i] << 8) / Nt;
        atomicAdd(&hist[b], 1);
    }
    __syncthreads();
    if (hist[tid]) atomicAdd(&bcnt[k * 256 + tid], hist[tid]);

    // ---- fused cast: grid-stride over all 223000*16 f16x8 slots
    const int nb = gridDim.x * gridDim.y;                 // 1107
    const int bid = blockIdx.y * gridDim.x + blockIdx.x;
    const int total = 223000 * 16;
    for (int i = bid * 256 + tid; i < total; i += nb * 256) {
        int row = i >> 4, c8 = i & 15;
        const float* src;
        if (row < 200000)      src = x0 + (size_t)row * D;
        else if (row < 203000) src = x1 + (size_t)(row - 200000) * D;
        else                   src = x2 + (size_t)(row - 203000) * D;
        f32x4 v0 = ((const f32x4*)src)[c8 * 2];
        f32x4 v1 = ((const f32x4*)src)[c8 * 2 + 1];
        f16x8 h;
        #pragma unroll
        for (int j = 0; j < 4; ++j) { h[j] = (f16)v0[j]; h[4 + j] = (f16)v1[j]; }
        ((f16x8*)(y + (size_t)row * D))[c8] = h;
    }
}

__global__ void bucket_scan(const int* __restrict__ bcnt,
                            int* __restrict__ bbase, int* __restrict__ bcursor) {
    __shared__ int sb[256];
    int t = threadIdx.x;
    int loc[9];
    int s = 0;
    #pragma unroll
    for (int j = 0; j < 9; ++j) { loc[j] = bcnt[t * 9 + j]; s += loc[j]; }
    sb[t] = s; __syncthreads();
    int v = s;
    for (int off = 1; off < 256; off <<= 1) {
        int u = (t >= off) ? sb[t - off] : 0;
        __syncthreads();
        sb[t] += u;
        __syncthreads();
    }
    int pre = sb[t] - v;
    #pragma unroll
    for (int j = 0; j < 9; ++j) {
        bbase[t * 9 + j] = pre;
        bcursor[t * 9 + j] = pre;
        pre += loc[j];
    }
    if (t == 255) bbase[2304] = pre;
}

__global__ __launch_bounds__(256) void bin_scatter(const int* __restrict__ ei,
                                                   int* __restrict__ bcursor,
                                                   int2* __restrict__ binned) {
    __shared__ int hist[256], gb[256], cur[256];
    int k = blockIdx.y, tid = threadIdx.x;
    const int* srcp = ei + (size_t)k * 2 * E_PER;
    const int* dstp = srcp + E_PER;
    unsigned Nt = (unsigned)d_NC[k % 3];
    int base = blockIdx.x * CH;
    int hi = min(base + CH, E_PER);
    hist[tid] = 0;
    __syncthreads();
    for (int i = base + tid; i < hi; i += 256) {
        unsigned b = ((unsigned)dstp[i] << 8) / Nt;
        atomicAdd(&hist[b], 1);
    }
    __syncthreads();
    gb[tid] = hist[tid] ? atomicAdd(&bcursor[k * 256 + tid], hist[tid]) : 0;
    cur[tid] = 0;
    __syncthreads();
    for (int i = base + tid; i < hi; i += 256) {
        int src = srcp[i], dst = dstp[i];
        unsigned b = ((unsigned)dst << 8) / Nt;
        int r = atomicAdd(&cur[b], 1);
        binned[(size_t)gb[b] + r] = make_int2(src, dst);
    }
}

__global__ __launch_bounds__(256) void fine_fill(const int2* __restrict__ binned,
                                                 const int* __restrict__ bbase,
                                                 int* __restrict__ rowstart,
                                                 int* __restrict__ ssrc) {
    __shared__ int rcnt[784];
    __shared__ int excl[784];
    __shared__ int scur[784];
    __shared__ int sb[256];
    int k = blockIdx.y, b = blockIdx.x, tid = threadIdx.x;
    int Nt = d_NC[k % 3];
    int segb = d_SEGB[k];
    int row_lo = (b * Nt + 255) >> 8;
    int row_hi = ((b + 1) * Nt + 255) >> 8;
    int nrows = row_hi - row_lo;
    int ebase = bbase[k * 256 + b];
    int eend  = bbase[k * 256 + b + 1];
    for (int i = tid; i < nrows; i += 256) rcnt[i] = 0;
    __syncthreads();
    for (int e = ebase + tid; e < eend; e += 256)
        atomicAdd(&rcnt[binned[e].y - row_lo], 1);
    __syncthreads();
    int stride = (nrows + 255) >> 8;
    int lo = tid * stride;
    int hi2 = min(lo + stride, nrows);
    int s = 0;
    for (int i = lo; i < hi2; ++i) s += rcnt[i];
    sb[tid] = s; __syncthreads();
    int v = s;
    for (int off = 1; off < 256; off <<= 1) {
        int u = (tid >= off) ? sb[tid - off] : 0;
        __syncthreads();
        sb[tid] += u;
        __syncthreads();
    }
    int pre = sb[tid] - v;
    for (int i = lo; i < hi2; ++i) {
        excl[i] = pre;
        scur[i] = pre;
        pre += rcnt[i];
    }
    __syncthreads();
    for (int i = tid; i < nrows; i += 256)
        rowstart[segb + row_lo + i] = ebase + excl[i];
    if (k == 8 && b == 255 && tid == 0) rowstart[TOT_ROWS] = eend;
    for (int e = ebase + tid; e < eend; e += 256) {
        int2 ed = binned[e];
        int r = atomicAdd(&scur[ed.y - row_lo], 1);
        ssrc[ebase + r] = ed.x;
    }
}

// ----------------------------------------------------- aggregate, all 9 k
__global__ __launch_bounds__(256) void aggregate_all(const f16* __restrict__ x16,
                                                     const int* __restrict__ rowstart,
                                                     const int* __restrict__ ssrc,
                                                     char* __restrict__ slabs,
                                                     const float* __restrict__ eps9) {
    __shared__ float part[4][128];
    int g = blockIdx.x;
    int k = 0;
    #pragma unroll
    for (int j = 1; j < 9; ++j) if (g >= d_AOFF[j]) k = j;
    int b = g - d_AOFF[k];
    int s = k / 3, t = k % 3;
    int N = d_NC[t];
    const int* rs = rowstart + d_SEGB[k];
    const f16* xsrc = x16 + (size_t)d_XB[s] * D;
    const f16* xt   = x16 + (size_t)d_XB[t] * D;
    char* slab = slabs + (size_t)s * SLABSZ + (size_t)d_XB[t] * 256;
    float epsv = 1.0f + eps9[k];
    int tid  = threadIdx.x;
    int lane = tid & 63;
    int w    = tid >> 6;
    int grp  = lane >> 4;
    int cs   = lane & 15;

    if (t != 1) {
        int row = (b << 4) + (tid >> 4);
        if (row >= N) return;          // exact grids; no barrier in this path
        int e0 = rs[row], e1 = rs[row + 1];
        f16x8 xv = ((const f16x8*)(xt + (size_t)row * D))[cs];
        float acc[8];
        #pragma unroll
        for (int j = 0; j < 8; ++j) acc[j] = epsv * (float)xv[j];
        int e = e0;
        for (; e + 3 < e1; e += 4) {
            int s0 = ssrc[e], s1 = ssrc[e + 1], s2 = ssrc[e + 2], s3 = ssrc[e + 3];
            f16x8 v0 = ((const f16x8*)(xsrc + (size_t)s0 * D))[cs];
            f16x8 v1 = ((const f16x8*)(xsrc + (size_t)s1 * D))[cs];
            f16x8 v2 = ((const f16x8*)(xsrc + (size_t)s2 * D))[cs];
            f16x8 v3 = ((const f16x8*)(xsrc + (size_t)s3 * D))[cs];
            #pragma unroll
            for (int j = 0; j < 8; ++j)
                acc[j] += ((float)v0[j] + (float)v1[j]) + ((float)v2[j] + (float)v3[j]);
        }
        if (e + 1 < e1) {
            int s0 = ssrc[e], s1 = ssrc[e + 1];
            f16x8 v0 = ((const f16x8*)(xsrc + (size_t)s0 * D))[cs];
            f16x8 v1 = ((const f16x8*)(xsrc + (size_t)s1 * D))[cs];
            #pragma unroll
            for (int j = 0; j < 8; ++j) acc[j] += (float)v0[j] + (float)v1[j];
            e += 2;
        }
        if (e < e1) {
            int s0 = ssrc[e];
            f16x8 v0 = ((const f16x8*)(xsrc + (size_t)s0 * D))[cs];
            #pragma unroll
            for (int j = 0; j < 8; ++j) acc[j] += (float)v0[j];
        }
        f16x8 h;
        #pragma unroll
        for (int j = 0; j < 8; ++j) h[j] = (f16)acc[j];
        ((f16x8*)(slab + (size_t)row * 256))[cs] = h;
    } else {
        int row = b;
        int estart = w * 4 + grp, estep = 16;
        float acc[8];
        #pragma unroll
        for (int j = 0; j < 8; ++j) acc[j] = 0.f;
        int e1 = rs[row + 1];
        int e  = rs[row] + estart;
        for (; e + 3 * estep < e1; e += 4 * estep) {
            int s0 = ssrc[e], s1 = ssrc[e + estep], s2 = ssrc[e + 2 * estep], s3 = ssrc[e + 3 * estep];
            f16x8 v0 = ((const f16x8*)(xsrc + (size_t)s0 * D))[cs];
            f16x8 v1 = ((const f16x8*)(xsrc + (size_t)s1 * D))[cs];
            f16x8 v2 = ((const f16x8*)(xsrc + (size_t)s2 * D))[cs];
            f16x8 v3 = ((const f16x8*)(xsrc + (size_t)s3 * D))[cs];
            #pragma unroll
            for (int j = 0; j < 8; ++j)
                acc[j] += ((float)v0[j] + (float)v1[j]) + ((float)v2[j] + (float)v3[j]);
        }
        for (; e < e1; e += estep) {
            int s0 = ssrc[e];
            f16x8 v0 = ((const f16x8*)(xsrc + (size_t)s0 * D))[cs];
            #pragma unroll
            for (int j = 0; j < 8; ++j) acc[j] += (float)v0[j];
        }
        #pragma unroll
        for (int j = 0; j < 8; ++j) {
            acc[j] += __shfl_xor(acc[j], 16);
            acc[j] += __shfl_xor(acc[j], 32);
        }
        if (lane < 16) {
            #pragma unroll
            for (int j = 0; j < 8; ++j) part[w][cs * 8 + j] = acc[j];
        }
        __syncthreads();
        if (w == 0 && lane < 16) {
            f16x8 xv = ((const f16x8*)(xt + (size_t)row * D))[cs];
            f16x8 h;
            #pragma unroll
            for (int j = 0; j < 8; ++j) {
                float v = (part[0][cs*8+j] + part[1][cs*8+j]) + (part[2][cs*8+j] + part[3][cs*8+j]);
                h[j] = (f16)(v + epsv * (float)xv[j]);
            }
            ((f16x8*)(slab + (size_t)row * 256))[cs] = h;
        }
    }
}

// -------------------------------------------------------------- layer-1 GEMM
// grid (1744, 3). 128-row tiles (measured-faster shape, r7). Stage slab rows
// via global_load_lds with pre-swizzled source; barrier; MFMA (2 acc sets);
// epilogue: bias + stats + z1 writeback.
__global__ __launch_bounds__(256) void gemm_l1(char* __restrict__ slabs,
                                               const f16* __restrict__ Wth,
                                               const float* __restrict__ bias,
                                               float* __restrict__ partials) {
    __shared__ alignas(16) char atile[128 * 256];
    __shared__ float wst[4][256];
    const int tid  = threadIdx.x;
    const int lane = tid & 63;
    const int w    = tid >> 6;
    const int s    = blockIdx.y;
    int t, tl;
    tile_map(blockIdx.x, t, tl);
    const int N = d_NC[t];
    const int row0 = tl * 128;
    char* slab = slabs + (size_t)s * SLABSZ + (size_t)d_XB[t] * 256;

    #pragma unroll
    for (int p = 0; p < 8; ++p) {
        int r  = p * 16 + (tid >> 4);
        int c8 = tid & 15;
        int row = row0 + r;
        if (row >= N) row = N - 1;   // clamp: garbage masked in epilogue
        const char* src = slab + (size_t)row * 256 + (unsigned)((c8 * 16) ^ ((r & 7) << 4));
        __builtin_amdgcn_global_load_lds(
            (const __attribute__((address_space(1))) void*)src,
            (__attribute__((address_space(3))) void*)(atile + p * 4096 + w * 1024),
            16, 0, 0);
    }
    __syncthreads();

    const f16* Wt = Wth + (size_t)s * 16384;
    f32x4 acc0[8], acc1[8];
    #pragma unroll
    for (int ct = 0; ct < 8; ++ct) {
        acc0[ct] = (f32x4){0.f, 0.f, 0.f, 0.f};
        acc1[ct] = (f32x4){0.f, 0.f, 0.f, 0.f};
    }
    const int arow0 = (w << 5) + (lane & 15);
    const int arow1 = arow0 + 16;
    const int kq = (lane >> 4) * 8;
    #pragma unroll
    for (int ks = 0; ks < 4; ++ks) {
        f16x8 af0 = *(const f16x8*)(atile + a_swz(arow0, (ks * 32 + kq) * 2));
        f16x8 af1 = *(const f16x8*)(atile + a_swz(arow1, (ks * 32 + kq) * 2));
        #pragma unroll
        for (int ct = 0; ct < 8; ++ct) {
            f16x8 bf = *(const f16x8*)(Wt + (size_t)(ct * 16 + (lane & 15)) * D + ks * 32 + kq);
            acc0[ct] = __builtin_amdgcn_mfma_f32_16x16x32_f16(af0, bf, acc0[ct], 0, 0, 0);
            acc1[ct] = __builtin_amdgcn_mfma_f32_16x16x32_f16(af1, bf, acc1[ct], 0, 0, 0);
        }
    }

    // epilogue: stats + z->LDS (wave-local rows), then coalesced writeback
    const int col_lo = lane & 15;
    const int lrb0 = (w << 5) + ((lane >> 4) << 2);
    #pragma unroll
    for (int ct = 0; ct < 8; ++ct) {
        int col = ct * 16 + col_lo;
        float bv = bias[s * D + col];
        float s_ = 0.f, q_ = 0.f;
        #pragma unroll
        for (int r = 0; r < 4; ++r) {
            int lrow = lrb0 + r;
            float val = acc0[ct][r] + bv;
            if (row0 + lrow < N) { s_ += val; q_ += val * val; }
            *(f16*)(atile + a_swz(lrow, col * 2)) = (f16)val;
        }
        #pragma unroll
        for (int r = 0; r < 4; ++r) {
            int lrow = lrb0 + 16 + r;
            float val = acc1[ct][r] + bv;
            if (row0 + lrow < N) { s_ += val; q_ += val * val; }
            *(f16*)(atile + a_swz(lrow, col * 2)) = (f16)val;
        }
        s_ += __shfl_xor(s_, 16); q_ += __shfl_xor(q_, 16);
        s_ += __shfl_xor(s_, 32); q_ += __shfl_xor(q_, 32);
        if (lane < 16) { wst[w][col] = s_; wst[w][128 + col] = q_; }
    }
    __syncthreads();

    #pragma unroll
    for (int p = 0; p < 8; ++p) {
        int r  = p * 16 + (tid >> 4);
        int c8 = tid & 15;
        int row = row0 + r;
        if (row < N)
            *(f16x8*)(slab + (size_t)row * 256 + c8 * 16) = *(const f16x8*)(atile + a_swz(r, c8 * 16));
    }
    float pv = wst[0][tid] + wst[1][tid] + wst[2][tid] + wst[3][tid];
    partials[((size_t)blockIdx.x * 3 + s) * 256 + tid] = pv;
}

// -------------------------------------------------------------- layer-2 GEMM
// grid (1744, 3). 128-row tiles, reg-staged affine+relu transform (r7 shape,
// measured 175 us).
__global__ __launch_bounds__(256) void gemm_l2(char* __restrict__ slabs,
                                               const f16* __restrict__ Wth2,
                                               const float* __restrict__ bias,
                                               const float* __restrict__ affa,
                                               const float* __restrict__ affc,
                                               float* __restrict__ partials) {
    __shared__ alignas(16) char atile[128 * 256];
    __shared__ float wst[4][256];
    const int tid  = threadIdx.x;
    const int lane = tid & 63;
    const int w    = tid >> 6;
    const int s    = blockIdx.y;
    int t, tl;
    tile_map(blockIdx.x, t, tl);
    const int N = d_NC[t];
    const int row0 = tl * 128;
    const int k = s * 3 + t;
    char* slab = slabs + (size_t)s * SLABSZ + (size_t)d_XB[t] * 256;
    const int c8 = tid & 15;

    f32x4 a0 = ((const f32x4*)(affa + k * 128))[c8 * 2];
    f32x4 a1 = ((const f32x4*)(affa + k * 128))[c8 * 2 + 1];
    f32x4 c0 = ((const f32x4*)(affc + k * 128))[c8 * 2];
    f32x4 c1 = ((const f32x4*)(affc + k * 128))[c8 * 2 + 1];

    // T14 split: issue all loads, then transform + LDS write
    f16x8 zv[8];
    #pragma unroll
    for (int p = 0; p < 8; ++p) {
        int r = p * 16 + (tid >> 4);
        int row = row0 + r;
        zv[p] = (row < N) ? ((const f16x8*)(slab + (size_t)row * 256))[c8]
                          : (f16x8){0, 0, 0, 0, 0, 0, 0, 0};
    }
    #pragma unroll
    for (int p = 0; p < 8; ++p) {
        int r = p * 16 + (tid >> 4);
        f16x8 hv;
        #pragma unroll
        for (int j = 0; j < 4; ++j) {
            float t0 = (float)zv[p][j] * a0[j] + c0[j];
            float t1 = (float)zv[p][4 + j] * a1[j] + c1[j];
            hv[j]     = (f16)(t0 > 0.f ? t0 : 0.f);
            hv[4 + j] = (f16)(t1 > 0.f ? t1 : 0.f);
        }
        *(f16x8*)(atile + a_swz(r, c8 * 16)) = hv;
    }
    __syncthreads();

    const f16* Wt = Wth2 + (size_t)s * 16384;
    f32x4 acc0[8], acc1[8];
    #pragma unroll
    for (int ct = 0; ct < 8; ++ct) {
        acc0[ct] = (f32x4){0.f, 0.f, 0.f, 0.f};
        acc1[ct] = (f32x4){0.f, 0.f, 0.f, 0.f};
    }
    const int arow0 = (w << 5) + (lane & 15);
    const int arow1 = arow0 + 16;
    const int kq = (lane >> 4) * 8;
    #pragma unroll
    for (int ks = 0; ks < 4; ++ks) {
        f16x8 af0 = *(const f16x8*)(atile + a_swz(arow0, (ks * 32 + kq) * 2));
        f16x8 af1 = *(const f16x8*)(atile + a_swz(arow1, (ks * 32 + kq) * 2));
        #pragma unroll
        for (int ct = 0; ct < 8; ++ct) {
            f16x8 bf = *(const f16x8*)(Wt + (size_t)(ct * 16 + (lane & 15)) * D + ks * 32 + kq);
            acc0[ct] = __builtin_amdgcn_mfma_f32_16x16x32_f16(af0, bf, acc0[ct], 0, 0, 0);
            acc1[ct] = __builtin_amdgcn_mfma_f32_16x16x32_f16(af1, bf, acc1[ct], 0, 0, 0);
        }
    }

    const int col_lo = lane & 15;
    const int lrb0 = (w << 5) + ((lane >> 4) << 2);
    #pragma unroll
    for (int ct = 0; ct < 8; ++ct) {
        int col = ct * 16 + col_lo;
        float bv = bias[s * D + col];
        float s_ = 0.f, q_ = 0.f;
        #pragma unroll
        for (int r = 0; r < 4; ++r) {
            int lrow = lrb0 + r;
            float val = acc0[ct][r] + bv;
            if (row0 + lrow < N) { s_ += val; q_ += val * val; }
            *(f16*)(atile + a_swz(lrow, col * 2)) = (f16)val;
        }
        #pragma unroll
        for (int r = 0; r < 4; ++r) {
            int lrow = lrb0 + 16 + r;
            float val = acc1[ct][r] + bv;
            if (row0 + lrow < N) { s_ += val; q_ += val * val; }
            *(f16*)(atile + a_swz(lrow, col * 2)) = (f16)val;
        }
        s_ += __shfl_xor(s_, 16); q_ += __shfl_xor(q_, 16);
        s_ += __shfl_xor(s_, 32); q_ += __shfl_xor(q_, 32);
        if (lane < 16) { wst[w][col] = s_; wst[w][128 + col] = q_; }
    }
    __syncthreads();

    #pragma unroll
    for (int p = 0; p < 8; ++p) {
        int r = p * 16 + (tid >> 4);
        int row = row0 + r;
        if (row < N)
            *(f16x8*)(slab + (size_t)row * 256 + c8 * 16) = *(const f16x8*)(atile + a_swz(r, c8 * 16));
    }
    float pv = wst[0][tid] + wst[1][tid] + wst[2][tid] + wst[3][tid];
    partials[((size_t)blockIdx.x * 3 + s) * 256 + tid] = pv;
}

// ----------------------------------------------------------- stats reduction
__global__ void bn_reduce(const float* __restrict__ partials,
                          float* __restrict__ partial2) {
    int k = blockIdx.y, tid = threadIdx.x;
    int s = k / 3, t = k % 3;
    int lo = d_TLO[t], hi = d_THI[t];
    float v = 0.f;
    for (int b = lo + blockIdx.x; b < hi; b += NR64)
        v += partials[((size_t)b * 3 + s) * 256 + tid];
    partial2[((size_t)k * NR64 + blockIdx.x) * 256 + tid] = v;
}

__global__ void bn_params(const float* __restrict__ partial2,
                          const float* __restrict__ g, const float* __restrict__ be,
                          float* __restrict__ affa, float* __restrict__ affc) {
    __shared__ float red[256];
    int k = blockIdx.x, tid = threadIdx.x;
    int s = k / 3, t = k % 3;
    float v = 0.f;
    #pragma unroll 4
    for (int b = 0; b < NR64; ++b)
        v += partial2[((size_t)k * NR64 + b) * 256 + tid];
    red[tid] = v;
    __syncthreads();
    if (tid < 128) {
        float sm = red[tid], q = red[128 + tid];
        float n = (float)d_NC[t];
        float mean = sm / n;
        float var  = q / n - mean * mean;
        float a = g[s * D + tid] * rsqrtf(var + 1e-5f);
        affa[k * 128 + tid] = a;
        affc[k * 128 + tid] = be[s * D + tid] - mean * a;
    }
}

// -------------------------------------------------- final accum, all rows
__global__ __launch_bounds__(256) void accum_all(const char* __restrict__ slabs,
                                                 const float* __restrict__ affa,
                                                 const float* __restrict__ affc,
                                                 float* __restrict__ outp) {
    const int total = 223000 * 16;
    for (int i = blockIdx.x * 256 + threadIdx.x; i < total; i += gridDim.x * 256) {
        int row = i >> 4;
        int c8  = i & 15;
        int t = (row < 200000) ? 0 : (row < 203000) ? 1 : 2;
        f32x4 o0 = {0.f, 0.f, 0.f, 0.f}, o1 = {0.f, 0.f, 0.f, 0.f};
        #pragma unroll
        for (int s = 0; s < 3; ++s) {
            int k = s * 3 + t;
            f16x8 z = ((const f16x8*)(slabs + (size_t)s * SLABSZ + (size_t)row * 256))[c8];
            f32x4 a0 = ((const f32x4*)(affa + k * 128))[c8 * 2];
            f32x4 a1 = ((const f32x4*)(affa + k * 128))[c8 * 2 + 1];
            f32x4 c0 = ((const f32x4*)(affc + k * 128))[c8 * 2];
            f32x4 c1 = ((const f32x4*)(affc + k * 128))[c8 * 2 + 1];
            #pragma unroll
            for (int j = 0; j < 4; ++j) {
                float t0 = (float)z[j] * a0[j] + c0[j];
                float t1 = (float)z[4 + j] * a1[j] + c1[j];
                o0[j] += t0 > 0.f ? t0 : 0.f;
                o1[j] += t1 > 0.f ? t1 : 0.f;
            }
        }
        ((f32x4*)(outp + (size_t)row * D))[c8 * 2]     = o0;
        ((f32x4*)(outp + (size_t)row * D))[c8 * 2 + 1] = o1;
    }
}

extern "C" void kernel_launch(void* const* d_in, const int* in_sizes, int n_in,
                              void* d_out, int out_size, void* d_ws, size_t ws_size,
                              hipStream_t stream) {
    const float* x0  = (const float*)d_in[0];
    const float* x1  = (const float*)d_in[1];
    const float* x2  = (const float*)d_in[2];
    const int*   ei  = (const int*)d_in[3];
    const float* W1  = (const float*)d_in[4];
    const float* b1  = (const float*)d_in[5];
    const float* g1  = (const float*)d_in[6];
    const float* be1 = (const float*)d_in[7];
    const float* W2  = (const float*)d_in[8];
    const float* b2  = (const float*)d_in[9];
    const float* g2  = (const float*)d_in[10];
    const float* be2 = (const float*)d_in[11];
    const float* eps9 = (const float*)d_in[12];
    float* outp = (float*)d_out;

    char* ws = (char*)d_ws;
    size_t off = 0;
    char* slabs = ws;                 off += 3 * SLABSZ;                   // 171.3 MB
    int2* binned = (int2*)slabs;      // 36 MB alias, consumed before slabs written
    f16* x16    = (f16*)(ws + off);   off += SLABSZ;                       // 57.1 MB
    int* ssrc   = (int*)(ws + off);   off += (size_t)9 * E_PER * 4;        // 18 MB
    int* rowstart = (int*)(ws + off); off += (size_t)(TOT_ROWS + 2) * 4;
    off = (off + 255) & ~(size_t)255;
    int* bcnt   = (int*)(ws + off);   off += 2308 * 4;
    int* bbase  = (int*)(ws + off);   off += 2308 * 4;
    int* bcursor= (int*)(ws + off);   off += 2308 * 4;
    off = (off + 255) & ~(size_t)255;
    float* partials = (float*)(ws + off); off += (size_t)1744 * 3 * 256 * 4;
    float* partial2 = (float*)(ws + off); off += (size_t)9 * NR64 * 256 * 4;
    float* aff1a = (float*)(ws + off); off += 9 * 128 * 4;
    float* aff1c = (float*)(ws + off); off += 9 * 128 * 4;
    float* aff2a = (float*)(ws + off); off += 9 * 128 * 4;
    float* aff2c = (float*)(ws + off); off += 9 * 128 * 4;
    f16* Wth = (f16*)(ws + off); off += (size_t)2 * 3 * 128 * 128 * sizeof(f16);

    // ---- setup
    precast<<<384, 256, 0, stream>>>(W1, W2, Wth);

    // ---- CSR build (pass 1 carries the x->f16 cast as a fused side job)
    hipMemsetAsync(bcnt, 0, 2308 * 4, stream);
    int nchunk = (E_PER + CH - 1) / CH;   // 123
    bucket_count<<<dim3(nchunk, 9), 256, 0, stream>>>(ei, bcnt, x0, x1, x2, x16);
    bucket_scan<<<1, 256, 0, stream>>>(bcnt, bbase, bcursor);
    bin_scatter<<<dim3(nchunk, 9), 256, 0, stream>>>(ei, bcursor, binned);
    fine_fill<<<dim3(256, 9), 256, 0, stream>>>(binned, bbase, rowstart, ssrc);

    // ---- aggregate all 9 (s,t) into slabs (folds (1+eps)*x_t)
    aggregate_all<<<50250, 256, 0, stream>>>(x16, rowstart, ssrc, slabs, eps9);

    gemm_l1<<<dim3(1744, 3), 256, 0, stream>>>(slabs, Wth, b1, partials);
    bn_reduce<<<dim3(NR64, 9), 256, 0, stream>>>(partials, partial2);
    bn_params<<<9, 256, 0, stream>>>(partial2, g1, be1, aff1a, aff1c);

    gemm_l2<<<dim3(1744, 3), 256, 0, stream>>>(slabs, Wth + 3 * 16384, b2,
                                               aff1a, aff1c, partials);
    bn_reduce<<<dim3(NR64, 9), 256, 0, stream>>>(partials, partial2);
    bn_params<<<9, 256, 0, stream>>>(partial2, g2, be2, aff2a, aff2c);

    accum_all<<<4096, 256, 0, stream>>>(slabs, aff2a, aff2c, outp);
}